// Round 11
// baseline (392.310 us; speedup 1.0000x reference)
//
#include <hip/hip_runtime.h>
#include <math.h>

#define NIN 128
#define NOUT 64
#define FEAT 256        // QL row: 256 bf16 = 512B
#define KHROW 512       // KH row: [K01 256B | H01 256B | K23 256B | H23 256B]

typedef __attribute__((ext_vector_type(8))) short short8;
typedef __attribute__((ext_vector_type(4))) float f32x4;

__device__ __forceinline__ unsigned short f2bf(float f) {
    unsigned u = __float_as_uint(f);
    u = (u + 0x7FFFu + ((u >> 16) & 1u)) >> 16;   // RTNE
    return (unsigned short)u;
}
__device__ __forceinline__ float bflo(unsigned u) {
    return __uint_as_float(u << 16);
}
__device__ __forceinline__ float bfhi(unsigned u) {
    return __uint_as_float(u & 0xffff0000u);
}

// ---------------- W fp32 -> bf16, pre-swizzled to MFMA A-fragment order ------
__global__ __launch_bounds__(256) void wconv_kernel(
    const float* __restrict__ Wq, const float* __restrict__ Wk,
    const float* __restrict__ Wh, unsigned short* __restrict__ Wsw)
{
    const int id = blockIdx.x * 256 + threadIdx.x;   // 12288 total
    const int lane = id & 63;
    const int kb   = (id >> 6) & 3;
    const int tile = (id >> 8) & 3;
    const int head = (id >> 10) & 3;
    const int mat  = id >> 12;
    const float* src = (mat == 0) ? Wq : (mat == 1) ? Wk : Wh;
    const int row   = tile * 16 + (lane & 15);
    const int kbase = kb * 32 + (lane >> 4) * 8;
    const float* sp = src + (size_t)(head * 64 + row) * NIN + kbase;
    const float4 a = *(const float4*)sp;
    const float4 b = *(const float4*)(sp + 4);
    uint4 w;
    w.x = (unsigned)f2bf(a.x) | ((unsigned)f2bf(a.y) << 16);
    w.y = (unsigned)f2bf(a.z) | ((unsigned)f2bf(a.w) << 16);
    w.z = (unsigned)f2bf(b.x) | ((unsigned)f2bf(b.y) << 16);
    w.w = (unsigned)f2bf(b.z) | ((unsigned)f2bf(b.w) << 16);
    *(uint4*)(Wsw + (size_t)id * 8) = w;
}

// ---------------- MFMA GEMM (BM=128, W staged via LDS) + fused degree/epos ---
__global__ __launch_bounds__(256) void gemm_mfma_kernel(
    const float* __restrict__ x, const unsigned short* __restrict__ Wsw,
    const float* __restrict__ bh,
    unsigned short* __restrict__ QL, unsigned short* __restrict__ KH, int N,
    const int* __restrict__ ei, int E, int* __restrict__ deg,
    int* __restrict__ epos, int GB)
{
    if (blockIdx.x >= GB) {   // ---- degree-count + edge-position side job ----
        for (int e = (blockIdx.x - GB) * 256 + threadIdx.x; e < E; e += 512 * 256)
            epos[e] = atomicAdd(&deg[ei[e]], 1);
        return;
    }

    __shared__ char smem[34816];   // xs staging; then bounce | W stage
    unsigned short (*xs)[136] = (unsigned short (*)[136])smem;

    const int nb = blockIdx.x * 128;
    const int t  = threadIdx.x;
    const int w  = t >> 6;
    const int l  = t & 63;

    #pragma unroll
    for (int j = 0; j < 16; ++j) {
        const int idx = j * 256 + t;
        const int row = idx >> 5;
        const int c4  = idx & 31;
        float4 xv = make_float4(0.f, 0.f, 0.f, 0.f);
        if (nb + row < N)
            xv = *(const float4*)(x + (size_t)(nb + row) * NIN + c4 * 4);
        ushort4 pk;
        pk.x = f2bf(xv.x); pk.y = f2bf(xv.y); pk.z = f2bf(xv.z); pk.w = f2bf(xv.w);
        *(ushort4*)(&xs[row][c4 * 4]) = pk;
    }
    __syncthreads();

    short8 bfrx[2][4];
    #pragma unroll
    for (int ns = 0; ns < 2; ++ns)
        #pragma unroll
        for (int kb = 0; kb < 4; ++kb)
            bfrx[ns][kb] = *(const short8*)(
                &xs[w * 32 + ns * 16 + (l & 15)][kb * 32 + (l >> 4) * 8]);
    __syncthreads();   // reuse smem as bounce + W stage

    char* const sbw = smem + w * 4608;                       // 32 nodes x 144B
    unsigned short* const wl = (unsigned short*)(smem + 18432);  // 16KB W stage
    const int fsub = (l >> 4) * 4;

    for (int g = 0; g < 12; ++g) {
        const int mat  = g >> 2;
        const int head = g & 3;

        {
            const uint4* gw = (const uint4*)(Wsw + (size_t)g * 8192);
            uint4* wl4 = (uint4*)wl;
            #pragma unroll
            for (int j = 0; j < 4; ++j)
                wl4[j * 256 + t] = gw[j * 256 + t];
        }
        __syncthreads();

        #pragma unroll
        for (int tile = 0; tile < 4; ++tile) {
            f32x4 a0 = (f32x4){0.f, 0.f, 0.f, 0.f};
            f32x4 a1 = (f32x4){0.f, 0.f, 0.f, 0.f};
            #pragma unroll
            for (int kb = 0; kb < 4; ++kb) {
                const short8 afrw = *(const short8*)(
                    wl + (((tile * 4 + kb) << 9) + (l << 3)));
                a0 = __builtin_amdgcn_mfma_f32_16x16x32_bf16(afrw, bfrx[0][kb], a0, 0, 0, 0);
                a1 = __builtin_amdgcn_mfma_f32_16x16x32_bf16(afrw, bfrx[1][kb], a1, 0, 0, 0);
            }
            #pragma unroll
            for (int ns = 0; ns < 2; ++ns) {
                const f32x4 av = ns ? a1 : a0;
                float v0 = av[0], v1 = av[1], v2 = av[2], v3 = av[3];
                const int node = (l & 15) + ns * 16;
                if (mat == 2) {
                    const float4 bv = *(const float4*)(bh + head * NOUT + tile * 16 + fsub);
                    v0 += bv.x; v1 += bv.y; v2 += bv.z; v3 += bv.w;
                } else {
                    v0 = (v0 > 0.f) ? v0 : 0.2f * v0;
                    v1 = (v1 > 0.f) ? v1 : 0.2f * v1;
                    v2 = (v2 > 0.f) ? v2 : 0.2f * v2;
                    v3 = (v3 > 0.f) ? v3 : 0.2f * v3;
                }
                uint2 pk;
                pk.x = (unsigned)f2bf(v0) | ((unsigned)f2bf(v1) << 16);
                pk.y = (unsigned)f2bf(v2) | ((unsigned)f2bf(v3) << 16);
                *(uint2*)(sbw + node * 144 + (tile * 16 + fsub) * 2) = pk;
            }
        }

        // store: 8 nodes per instruction, 1KB fully-contiguous per wave op
        #pragma unroll
        for (int jj = 0; jj < 4; ++jj) {
            const int node  = (l >> 3) + jj * 8;
            const int gnode = nb + w * 32 + node;
            const uint4 v = *(const uint4*)(sbw + node * 144 + (l & 7) * 16);
            if (gnode < N) {
                char* ob;
                if (mat == 0) {
                    ob = (char*)QL + (size_t)gnode * 512 + head * 128;
                } else {
                    // head-pair layout: [K01|H01|K23|H23], 128B per head-half
                    const int pb = (head >> 1) * 512 + (head & 1) * 128
                                 + (mat == 2 ? 256 : 0);
                    ob = (char*)KH + (size_t)gnode * 1024 + pb;
                }
                *(uint4*)(ob + (l & 7) * 16) = v;
            }
        }
        __syncthreads();
    }
}

// ---------------- multi-block scan ----------------
__global__ __launch_bounds__(1024) void bsum_kernel(const int* __restrict__ deg, int N,
                                                    int* __restrict__ bsum)
{
    __shared__ int wsum[16];
    const int t = threadIdx.x;
    const int idx = blockIdx.x * 1024 + t;
    int v = (idx < N) ? deg[idx] : 0;
    #pragma unroll
    for (int off = 1; off < 64; off <<= 1) v += __shfl_xor(v, off);
    if ((t & 63) == 0) wsum[t >> 6] = v;
    __syncthreads();
    if (t < 16) {
        int s = wsum[t];
        #pragma unroll
        for (int off = 1; off < 16; off <<= 1) s += __shfl_xor(s, off);
        if (t == 0) bsum[blockIdx.x] = s;
    }
}

__global__ __launch_bounds__(1024) void bscan_kernel(int* __restrict__ bsum, int NB,
                                                     int* __restrict__ rowstart, int N)
{
    __shared__ int wsum[16];
    const int t = threadIdx.x, lane = t & 63, wid = t >> 6;
    const int v = (t < NB) ? bsum[t] : 0;
    int s = v;
    #pragma unroll
    for (int off = 1; off < 64; off <<= 1) {
        int u = __shfl_up(s, off);
        if (lane >= off) s += u;
    }
    if (lane == 63) wsum[wid] = s;
    __syncthreads();
    if (wid == 0 && lane < 16) {
        int ss = wsum[lane];
        #pragma unroll
        for (int off = 1; off < 16; off <<= 1) {
            int u = __shfl_up(ss, off);
            if (lane >= off) ss += u;
        }
        wsum[lane] = ss;
    }
    __syncthreads();
    const int woff = (wid == 0) ? 0 : wsum[wid - 1];
    if (t < NB) bsum[t] = s + woff - v;
    if (t == 1023) rowstart[N] = s + woff;
}

__global__ __launch_bounds__(1024) void scan_apply_kernel(
    const int* __restrict__ deg, const int* __restrict__ bsum, int N,
    int* __restrict__ rowstart)
{
    __shared__ int wsum[16];
    const int t = threadIdx.x, lane = t & 63, wid = t >> 6;
    const int idx = blockIdx.x * 1024 + t;
    const int v = (idx < N) ? deg[idx] : 0;
    int s = v;
    #pragma unroll
    for (int off = 1; off < 64; off <<= 1) {
        int u = __shfl_up(s, off);
        if (lane >= off) s += u;
    }
    if (lane == 63) wsum[wid] = s;
    __syncthreads();
    if (wid == 0 && lane < 16) {
        int ss = wsum[lane];
        #pragma unroll
        for (int off = 1; off < 16; off <<= 1) {
            int u = __shfl_up(ss, off);
            if (lane >= off) ss += u;
        }
        wsum[lane] = ss;
    }
    __syncthreads();
    const int woff = (wid == 0) ? 0 : wsum[wid - 1];
    if (idx < N) rowstart[idx] = s + woff - v + bsum[blockIdx.x];
}

// ---------------- CSR fill (no atomics: position precomputed) ----------------
__global__ __launch_bounds__(256) void fill_kernel(const int* __restrict__ ei, int E,
                                                   const int* __restrict__ rowstart,
                                                   const int* __restrict__ epos,
                                                   int* __restrict__ csr_col)
{
    const int e = blockIdx.x * 256 + threadIdx.x;
    if (e < E)
        csr_col[rowstart[ei[e]] + epos[e]] = ei[E + e];
}

// ---------------- per-row col sort (perf hint: temporal gather locality) -----
// One wave per node; 64-lane bitonic network. Rows with deg>64 left unsorted
// (correctness is order-invariant; sorting is purely a cache-locality hint).
__global__ __launch_bounds__(256) void sort_kernel(const int* __restrict__ rowstart,
                                                   int* __restrict__ csr_col, int N)
{
    const int n = blockIdx.x * 4 + (threadIdx.x >> 6);
    if (n >= N) return;
    const int l  = threadIdx.x & 63;
    const int s0 = rowstart[n];
    const int deg = rowstart[n + 1] - s0;
    if (deg <= 1 || deg > 64) return;

    int v = (l < deg) ? csr_col[s0 + l] : 0x7fffffff;
    #pragma unroll
    for (int k = 2; k <= 64; k <<= 1) {
        #pragma unroll
        for (int j = k >> 1; j > 0; j >>= 1) {
            const int partner = __shfl_xor(v, j);
            const bool up = ((l & k) == 0);
            const bool keepmin = (((l & j) == 0) == up);
            v = keepmin ? min(v, partner) : max(v, partner);
        }
    }
    if (l < deg) csr_col[s0 + l] = v;
}

// ---------------- fused attention, head-pair pass hp (0: heads 0-1, 1: 2-3) --
// lane: g=l>>4 edge slot, h2=(l>>3)&1 head-in-pair, dr=l&7 -> dims [dr*8,dr*8+8)
__global__ __launch_bounds__(256) void attn_kernel(
    const unsigned short* __restrict__ QL, const unsigned short* __restrict__ KH,
    const int* __restrict__ rowstart, const int* __restrict__ csr_col,
    float* __restrict__ out, int N, int hp)
{
    const int n = blockIdx.x * 4 + (threadIdx.x >> 6);
    if (n >= N) return;
    const int l  = threadIdx.x & 63;
    const int g  = l >> 4;
    const int h2 = (l >> 3) & 1;
    const int dr = l & 7;
    const int kboff = hp * 512 + h2 * 128 + dr * 16;        // K byte offset in row
    const int hboff = kboff + 256;                           // H byte offset

    // Q fragment: 8 dims of head (hp*2+h2)
    float qf[8];
    {
        const uint4 qv = *(const uint4*)(QL + (size_t)n * FEAT
                                         + (hp * 2 + h2) * 64 + dr * 8);
        unsigned qs[4] = {qv.x, qv.y, qv.z, qv.w};
        #pragma unroll
        for (int tt = 0; tt < 4; ++tt) {
            qf[2 * tt]     = bflo(qs[tt]);
            qf[2 * tt + 1] = bfhi(qs[tt]);
        }
    }

    const int s0 = rowstart[n];
    const int s1 = rowstart[n + 1];

    float acc[8];
    #pragma unroll
    for (int j = 0; j < 8; ++j) acc[j] = 0.f;
    float z = 0.f;

    for (int i = s0; i < s1; i += 4) {
        const int eidx = i + g;
        if (eidx < s1) {
            const int c = csr_col[eidx];
            const char* base = (const char*)KH + (size_t)c * 1024;
            const uint4 ku = *(const uint4*)(base + kboff);   // 16B K (8 dims)
            const uint4 hu = *(const uint4*)(base + hboff);   // 16B H (8 dims)

            unsigned ks[4] = {ku.x, ku.y, ku.z, ku.w};
            float p = 0.f;
            #pragma unroll
            for (int tt = 0; tt < 4; ++tt) {
                p = fmaf(qf[2 * tt],     bflo(ks[tt]), p);
                p = fmaf(qf[2 * tt + 1], bfhi(ks[tt]), p);
            }
            // reduce across the 8 dr lanes (bits 0-2)
            p += __shfl_xor(p, 1);
            p += __shfl_xor(p, 2);
            p += __shfl_xor(p, 4);

            const float e = __expf(p * 0.125f);   // no-max softmax (shift-inv.)
            z += e;
            unsigned hs[4] = {hu.x, hu.y, hu.z, hu.w};
            #pragma unroll
            for (int tt = 0; tt < 4; ++tt) {
                acc[2 * tt]     = fmaf(e, bflo(hs[tt]), acc[2 * tt]);
                acc[2 * tt + 1] = fmaf(e, bfhi(hs[tt]), acc[2 * tt + 1]);
            }
        }
    }

    // sum across the 4 edge slots (bits 4,5)
    z += __shfl_xor(z, 16);
    z += __shfl_xor(z, 32);
    #pragma unroll
    for (int j = 0; j < 8; ++j) {
        acc[j] += __shfl_xor(acc[j], 16);
        acc[j] += __shfl_xor(acc[j], 32);
    }
    // normalize per head, then sum the head pair (bit 3)
    const float inv = 1.f / (z + 1e-8f);
    #pragma unroll
    for (int j = 0; j < 8; ++j) {
        float r = acc[j] * inv;
        r += __shfl_xor(r, 8);
        acc[j] = r;
    }
    if (l < 8) {   // g=0,h2=0, dr=l: dims [l*8, l*8+8)
        float* ob = out + (size_t)n * NOUT + l * 8;
        if (hp == 0) {   // pass A: write head-pair partial sum
            *(float4*)(ob + 0) = make_float4(acc[0], acc[1], acc[2], acc[3]);
            *(float4*)(ob + 4) = make_float4(acc[4], acc[5], acc[6], acc[7]);
        } else {         // pass B: add + final mean over 4 heads
            const float4 p0 = *(const float4*)(ob + 0);
            const float4 p1 = *(const float4*)(ob + 4);
            *(float4*)(ob + 0) = make_float4((p0.x + acc[0]) * 0.25f,
                                             (p0.y + acc[1]) * 0.25f,
                                             (p0.z + acc[2]) * 0.25f,
                                             (p0.w + acc[3]) * 0.25f);
            *(float4*)(ob + 4) = make_float4((p1.x + acc[4]) * 0.25f,
                                             (p1.y + acc[5]) * 0.25f,
                                             (p1.z + acc[6]) * 0.25f,
                                             (p1.w + acc[7]) * 0.25f);
        }
    }
}

// ---------------- launch ----------------
extern "C" void kernel_launch(void* const* d_in, const int* in_sizes, int n_in,
                              void* d_out, int out_size, void* d_ws, size_t ws_size,
                              hipStream_t stream)
{
    const float* x  = (const float*)d_in[0];
    const int*   ei = (const int*)d_in[1];
    const float* Wq = (const float*)d_in[2];
    const float* Wk = (const float*)d_in[3];
    const float* Wh = (const float*)d_in[4];
    const float* bh = (const float*)d_in[5];
    float* out = (float*)d_out;
    const int N = in_sizes[0] / NIN;   // 100000
    const int E = in_sizes[1] / 2;     // 1600000

    char* p = (char*)d_ws;
    auto alloc = [&](size_t bytes) {
        char* r = p;
        p += (bytes + 255) & ~(size_t)255;
        return r;
    };
    unsigned short* QL  = (unsigned short*)alloc((size_t)N * FEAT * 2);
    unsigned short* KH  = (unsigned short*)alloc((size_t)N * KHROW * 2);
    unsigned short* Wsw = (unsigned short*)alloc((size_t)12288 * 8 * 2);
    int* deg      = (int*)alloc((size_t)N * 4);
    int* rowstart = (int*)alloc((size_t)(N + 1) * 4);
    int* epos     = (int*)alloc((size_t)E * 4);
    int* csr_col  = (int*)alloc((size_t)(E + 8) * 4);
    int* bsum     = (int*)alloc((size_t)1024 * 4);

    const int NB = (N + 1023) / 1024;   // 98
    const int GB = (N + 127) / 128;     // 782 gemm blocks

    hipMemsetAsync(deg, 0, (size_t)N * 4, stream);

    wconv_kernel<<<48, 256, 0, stream>>>(Wq, Wk, Wh, Wsw);
    gemm_mfma_kernel<<<GB + 512, 256, 0, stream>>>(x, Wsw, bh, QL, KH, N,
                                                   ei, E, deg, epos, GB);
    bsum_kernel<<<NB, 1024, 0, stream>>>(deg, N, bsum);
    bscan_kernel<<<1, 1024, 0, stream>>>(bsum, NB, rowstart, N);
    scan_apply_kernel<<<NB, 1024, 0, stream>>>(deg, bsum, N, rowstart);
    fill_kernel<<<(E + 255) / 256, 256, 0, stream>>>(ei, E, rowstart, epos, csr_col);

    const int AB = (N + 3) / 4;
    sort_kernel<<<AB, 256, 0, stream>>>(rowstart, csr_col, N);

    // attention: two head-pair passes over col-sorted CSR
    attn_kernel<<<AB, 256, 0, stream>>>(QL, KH, rowstart, csr_col, out, N, 0);
    attn_kernel<<<AB, 256, 0, stream>>>(QL, KH, rowstart, csr_col, out, N, 1);
}

// Round 12
// 367.441 us; speedup vs baseline: 1.0677x; 1.0677x over previous
//
#include <hip/hip_runtime.h>
#include <math.h>

#define NIN 128
#define NOUT 64
#define FEAT 256        // QL row: 256 bf16 = 512B
#define KHROW 512       // KH row: [K01 256B | H01 256B | K23 256B | H23 256B]

typedef __attribute__((ext_vector_type(8))) short short8;
typedef __attribute__((ext_vector_type(4))) float f32x4;

__device__ __forceinline__ unsigned short f2bf(float f) {
    unsigned u = __float_as_uint(f);
    u = (u + 0x7FFFu + ((u >> 16) & 1u)) >> 16;   // RTNE
    return (unsigned short)u;
}
__device__ __forceinline__ float bflo(unsigned u) {
    return __uint_as_float(u << 16);
}
__device__ __forceinline__ float bfhi(unsigned u) {
    return __uint_as_float(u & 0xffff0000u);
}

// ---------------- W fp32 -> bf16, pre-swizzled to MFMA A-fragment order ------
__global__ __launch_bounds__(256) void wconv_kernel(
    const float* __restrict__ Wq, const float* __restrict__ Wk,
    const float* __restrict__ Wh, unsigned short* __restrict__ Wsw)
{
    const int id = blockIdx.x * 256 + threadIdx.x;   // 12288 total
    const int lane = id & 63;
    const int kb   = (id >> 6) & 3;
    const int tile = (id >> 8) & 3;
    const int head = (id >> 10) & 3;
    const int mat  = id >> 12;
    const float* src = (mat == 0) ? Wq : (mat == 1) ? Wk : Wh;
    const int row   = tile * 16 + (lane & 15);
    const int kbase = kb * 32 + (lane >> 4) * 8;
    const float* sp = src + (size_t)(head * 64 + row) * NIN + kbase;
    const float4 a = *(const float4*)sp;
    const float4 b = *(const float4*)(sp + 4);
    uint4 w;
    w.x = (unsigned)f2bf(a.x) | ((unsigned)f2bf(a.y) << 16);
    w.y = (unsigned)f2bf(a.z) | ((unsigned)f2bf(a.w) << 16);
    w.z = (unsigned)f2bf(b.x) | ((unsigned)f2bf(b.y) << 16);
    w.w = (unsigned)f2bf(b.z) | ((unsigned)f2bf(b.w) << 16);
    *(uint4*)(Wsw + (size_t)id * 8) = w;
}

// ---------------- MFMA GEMM (BM=128, W staged via LDS) + fused degree/epos ---
__global__ __launch_bounds__(256) void gemm_mfma_kernel(
    const float* __restrict__ x, const unsigned short* __restrict__ Wsw,
    const float* __restrict__ bh,
    unsigned short* __restrict__ QL, unsigned short* __restrict__ KH, int N,
    const int* __restrict__ ei, int E, int* __restrict__ deg,
    int* __restrict__ epos, int GB)
{
    if (blockIdx.x >= GB) {   // ---- degree-count + edge-position side job ----
        for (int e = (blockIdx.x - GB) * 256 + threadIdx.x; e < E; e += 512 * 256)
            epos[e] = atomicAdd(&deg[ei[e]], 1);
        return;
    }

    __shared__ char smem[34816];   // xs staging; then bounce | W stage
    unsigned short (*xs)[136] = (unsigned short (*)[136])smem;

    const int nb = blockIdx.x * 128;
    const int t  = threadIdx.x;
    const int w  = t >> 6;
    const int l  = t & 63;

    #pragma unroll
    for (int j = 0; j < 16; ++j) {
        const int idx = j * 256 + t;
        const int row = idx >> 5;
        const int c4  = idx & 31;
        float4 xv = make_float4(0.f, 0.f, 0.f, 0.f);
        if (nb + row < N)
            xv = *(const float4*)(x + (size_t)(nb + row) * NIN + c4 * 4);
        ushort4 pk;
        pk.x = f2bf(xv.x); pk.y = f2bf(xv.y); pk.z = f2bf(xv.z); pk.w = f2bf(xv.w);
        *(ushort4*)(&xs[row][c4 * 4]) = pk;
    }
    __syncthreads();

    short8 bfrx[2][4];
    #pragma unroll
    for (int ns = 0; ns < 2; ++ns)
        #pragma unroll
        for (int kb = 0; kb < 4; ++kb)
            bfrx[ns][kb] = *(const short8*)(
                &xs[w * 32 + ns * 16 + (l & 15)][kb * 32 + (l >> 4) * 8]);
    __syncthreads();   // reuse smem as bounce + W stage

    char* const sbw = smem + w * 4608;                       // 32 nodes x 144B
    unsigned short* const wl = (unsigned short*)(smem + 18432);  // 16KB W stage
    const int fsub = (l >> 4) * 4;

    for (int g = 0; g < 12; ++g) {
        const int mat  = g >> 2;
        const int head = g & 3;

        {
            const uint4* gw = (const uint4*)(Wsw + (size_t)g * 8192);
            uint4* wl4 = (uint4*)wl;
            #pragma unroll
            for (int j = 0; j < 4; ++j)
                wl4[j * 256 + t] = gw[j * 256 + t];
        }
        __syncthreads();

        #pragma unroll
        for (int tile = 0; tile < 4; ++tile) {
            f32x4 a0 = (f32x4){0.f, 0.f, 0.f, 0.f};
            f32x4 a1 = (f32x4){0.f, 0.f, 0.f, 0.f};
            #pragma unroll
            for (int kb = 0; kb < 4; ++kb) {
                const short8 afrw = *(const short8*)(
                    wl + (((tile * 4 + kb) << 9) + (l << 3)));
                a0 = __builtin_amdgcn_mfma_f32_16x16x32_bf16(afrw, bfrx[0][kb], a0, 0, 0, 0);
                a1 = __builtin_amdgcn_mfma_f32_16x16x32_bf16(afrw, bfrx[1][kb], a1, 0, 0, 0);
            }
            #pragma unroll
            for (int ns = 0; ns < 2; ++ns) {
                const f32x4 av = ns ? a1 : a0;
                float v0 = av[0], v1 = av[1], v2 = av[2], v3 = av[3];
                const int node = (l & 15) + ns * 16;
                if (mat == 2) {
                    const float4 bv = *(const float4*)(bh + head * NOUT + tile * 16 + fsub);
                    v0 += bv.x; v1 += bv.y; v2 += bv.z; v3 += bv.w;
                } else {
                    v0 = (v0 > 0.f) ? v0 : 0.2f * v0;
                    v1 = (v1 > 0.f) ? v1 : 0.2f * v1;
                    v2 = (v2 > 0.f) ? v2 : 0.2f * v2;
                    v3 = (v3 > 0.f) ? v3 : 0.2f * v3;
                }
                uint2 pk;
                pk.x = (unsigned)f2bf(v0) | ((unsigned)f2bf(v1) << 16);
                pk.y = (unsigned)f2bf(v2) | ((unsigned)f2bf(v3) << 16);
                *(uint2*)(sbw + node * 144 + (tile * 16 + fsub) * 2) = pk;
            }
        }

        // store: 8 nodes per instruction, 1KB fully-contiguous per wave op
        #pragma unroll
        for (int jj = 0; jj < 4; ++jj) {
            const int node  = (l >> 3) + jj * 8;
            const int gnode = nb + w * 32 + node;
            const uint4 v = *(const uint4*)(sbw + node * 144 + (l & 7) * 16);
            if (gnode < N) {
                char* ob;
                if (mat == 0) {
                    ob = (char*)QL + (size_t)gnode * 512 + head * 128;
                } else {
                    // head-pair layout: [K01|H01|K23|H23], 128B per head-half
                    const int pb = (head >> 1) * 512 + (head & 1) * 128
                                 + (mat == 2 ? 256 : 0);
                    ob = (char*)KH + (size_t)gnode * 1024 + pb;
                }
                *(uint4*)(ob + (l & 7) * 16) = v;
            }
        }
        __syncthreads();
    }
}

// ---------------- multi-block scan ----------------
__global__ __launch_bounds__(1024) void bsum_kernel(const int* __restrict__ deg, int N,
                                                    int* __restrict__ bsum)
{
    __shared__ int wsum[16];
    const int t = threadIdx.x;
    const int idx = blockIdx.x * 1024 + t;
    int v = (idx < N) ? deg[idx] : 0;
    #pragma unroll
    for (int off = 1; off < 64; off <<= 1) v += __shfl_xor(v, off);
    if ((t & 63) == 0) wsum[t >> 6] = v;
    __syncthreads();
    if (t < 16) {
        int s = wsum[t];
        #pragma unroll
        for (int off = 1; off < 16; off <<= 1) s += __shfl_xor(s, off);
        if (t == 0) bsum[blockIdx.x] = s;
    }
}

__global__ __launch_bounds__(1024) void bscan_kernel(int* __restrict__ bsum, int NB,
                                                     int* __restrict__ rowstart, int N)
{
    __shared__ int wsum[16];
    const int t = threadIdx.x, lane = t & 63, wid = t >> 6;
    const int v = (t < NB) ? bsum[t] : 0;
    int s = v;
    #pragma unroll
    for (int off = 1; off < 64; off <<= 1) {
        int u = __shfl_up(s, off);
        if (lane >= off) s += u;
    }
    if (lane == 63) wsum[wid] = s;
    __syncthreads();
    if (wid == 0 && lane < 16) {
        int ss = wsum[lane];
        #pragma unroll
        for (int off = 1; off < 16; off <<= 1) {
            int u = __shfl_up(ss, off);
            if (lane >= off) ss += u;
        }
        wsum[lane] = ss;
    }
    __syncthreads();
    const int woff = (wid == 0) ? 0 : wsum[wid - 1];
    if (t < NB) bsum[t] = s + woff - v;
    if (t == 1023) rowstart[N] = s + woff;
}

__global__ __launch_bounds__(1024) void scan_apply_kernel(
    const int* __restrict__ deg, const int* __restrict__ bsum, int N,
    int* __restrict__ rowstart)
{
    __shared__ int wsum[16];
    const int t = threadIdx.x, lane = t & 63, wid = t >> 6;
    const int idx = blockIdx.x * 1024 + t;
    const int v = (idx < N) ? deg[idx] : 0;
    int s = v;
    #pragma unroll
    for (int off = 1; off < 64; off <<= 1) {
        int u = __shfl_up(s, off);
        if (lane >= off) s += u;
    }
    if (lane == 63) wsum[wid] = s;
    __syncthreads();
    if (wid == 0 && lane < 16) {
        int ss = wsum[lane];
        #pragma unroll
        for (int off = 1; off < 16; off <<= 1) {
            int u = __shfl_up(ss, off);
            if (lane >= off) ss += u;
        }
        wsum[lane] = ss;
    }
    __syncthreads();
    const int woff = (wid == 0) ? 0 : wsum[wid - 1];
    if (idx < N) rowstart[idx] = s + woff - v + bsum[blockIdx.x];
}

// ---------------- CSR fill (no atomics: position precomputed) ----------------
__global__ __launch_bounds__(256) void fill_kernel(const int* __restrict__ ei, int E,
                                                   const int* __restrict__ rowstart,
                                                   const int* __restrict__ epos,
                                                   int* __restrict__ csr_col)
{
    const int e = blockIdx.x * 256 + threadIdx.x;
    if (e < E)
        csr_col[rowstart[ei[e]] + epos[e]] = ei[E + e];
}

// ---------------- fused attention, head-pair pass hp (0: heads 0-1, 1: 2-3) --
// lane: g=l>>4 edge slot, h2=(l>>3)&1 head-in-pair, dr=l&7 -> dims [dr*8,dr*8+8)
__global__ __launch_bounds__(256) void attn_kernel(
    const unsigned short* __restrict__ QL, const unsigned short* __restrict__ KH,
    const int* __restrict__ rowstart, const int* __restrict__ csr_col,
    float* __restrict__ out, int N, int hp)
{
    const int n = blockIdx.x * 4 + (threadIdx.x >> 6);
    if (n >= N) return;
    const int l  = threadIdx.x & 63;
    const int g  = l >> 4;
    const int h2 = (l >> 3) & 1;
    const int dr = l & 7;
    const int kboff = hp * 512 + h2 * 128 + dr * 16;        // K byte offset in row
    const int hboff = kboff + 256;                           // H byte offset

    // Q fragment: 8 dims of head (hp*2+h2)
    float qf[8];
    {
        const uint4 qv = *(const uint4*)(QL + (size_t)n * FEAT
                                         + (hp * 2 + h2) * 64 + dr * 8);
        unsigned qs[4] = {qv.x, qv.y, qv.z, qv.w};
        #pragma unroll
        for (int tt = 0; tt < 4; ++tt) {
            qf[2 * tt]     = bflo(qs[tt]);
            qf[2 * tt + 1] = bfhi(qs[tt]);
        }
    }

    const int s0 = rowstart[n];
    const int s1 = rowstart[n + 1];

    float acc[8];
    #pragma unroll
    for (int j = 0; j < 8; ++j) acc[j] = 0.f;
    float z = 0.f;

    for (int i = s0; i < s1; i += 4) {
        const int eidx = i + g;
        if (eidx < s1) {
            const int c = csr_col[eidx];
            const char* base = (const char*)KH + (size_t)c * 1024;
            const uint4 ku = *(const uint4*)(base + kboff);   // 16B K (8 dims)
            const uint4 hu = *(const uint4*)(base + hboff);   // 16B H (8 dims)

            unsigned ks[4] = {ku.x, ku.y, ku.z, ku.w};
            float p = 0.f;
            #pragma unroll
            for (int tt = 0; tt < 4; ++tt) {
                p = fmaf(qf[2 * tt],     bflo(ks[tt]), p);
                p = fmaf(qf[2 * tt + 1], bfhi(ks[tt]), p);
            }
            // reduce across the 8 dr lanes (bits 0-2)
            p += __shfl_xor(p, 1);
            p += __shfl_xor(p, 2);
            p += __shfl_xor(p, 4);

            const float e = __expf(p * 0.125f);   // no-max softmax (shift-inv.)
            z += e;
            unsigned hs[4] = {hu.x, hu.y, hu.z, hu.w};
            #pragma unroll
            for (int tt = 0; tt < 4; ++tt) {
                acc[2 * tt]     = fmaf(e, bflo(hs[tt]), acc[2 * tt]);
                acc[2 * tt + 1] = fmaf(e, bfhi(hs[tt]), acc[2 * tt + 1]);
            }
        }
    }

    // sum across the 4 edge slots (bits 4,5)
    z += __shfl_xor(z, 16);
    z += __shfl_xor(z, 32);
    #pragma unroll
    for (int j = 0; j < 8; ++j) {
        acc[j] += __shfl_xor(acc[j], 16);
        acc[j] += __shfl_xor(acc[j], 32);
    }
    // normalize per head, then sum the head pair (bit 3)
    const float inv = 1.f / (z + 1e-8f);
    #pragma unroll
    for (int j = 0; j < 8; ++j) {
        float r = acc[j] * inv;
        r += __shfl_xor(r, 8);
        acc[j] = r;
    }
    if (l < 8) {   // g=0,h2=0, dr=l: dims [l*8, l*8+8)
        float* ob = out + (size_t)n * NOUT + l * 8;
        if (hp == 0) {   // pass A: write head-pair partial sum
            *(float4*)(ob + 0) = make_float4(acc[0], acc[1], acc[2], acc[3]);
            *(float4*)(ob + 4) = make_float4(acc[4], acc[5], acc[6], acc[7]);
        } else {         // pass B: add + final mean over 4 heads
            const float4 p0 = *(const float4*)(ob + 0);
            const float4 p1 = *(const float4*)(ob + 4);
            *(float4*)(ob + 0) = make_float4((p0.x + acc[0]) * 0.25f,
                                             (p0.y + acc[1]) * 0.25f,
                                             (p0.z + acc[2]) * 0.25f,
                                             (p0.w + acc[3]) * 0.25f);
            *(float4*)(ob + 4) = make_float4((p1.x + acc[4]) * 0.25f,
                                             (p1.y + acc[5]) * 0.25f,
                                             (p1.z + acc[6]) * 0.25f,
                                             (p1.w + acc[7]) * 0.25f);
        }
    }
}

// ---------------- launch ----------------
extern "C" void kernel_launch(void* const* d_in, const int* in_sizes, int n_in,
                              void* d_out, int out_size, void* d_ws, size_t ws_size,
                              hipStream_t stream)
{
    const float* x  = (const float*)d_in[0];
    const int*   ei = (const int*)d_in[1];
    const float* Wq = (const float*)d_in[2];
    const float* Wk = (const float*)d_in[3];
    const float* Wh = (const float*)d_in[4];
    const float* bh = (const float*)d_in[5];
    float* out = (float*)d_out;
    const int N = in_sizes[0] / NIN;   // 100000
    const int E = in_sizes[1] / 2;     // 1600000

    char* p = (char*)d_ws;
    auto alloc = [&](size_t bytes) {
        char* r = p;
        p += (bytes + 255) & ~(size_t)255;
        return r;
    };
    unsigned short* QL  = (unsigned short*)alloc((size_t)N * FEAT * 2);
    unsigned short* KH  = (unsigned short*)alloc((size_t)N * KHROW * 2);
    unsigned short* Wsw = (unsigned short*)alloc((size_t)12288 * 8 * 2);
    int* deg      = (int*)alloc((size_t)N * 4);
    int* rowstart = (int*)alloc((size_t)(N + 1) * 4);
    int* epos     = (int*)alloc((size_t)E * 4);
    int* csr_col  = (int*)alloc((size_t)(E + 8) * 4);
    int* bsum     = (int*)alloc((size_t)1024 * 4);

    const int NB = (N + 1023) / 1024;   // 98
    const int GB = (N + 127) / 128;     // 782 gemm blocks

    hipMemsetAsync(deg, 0, (size_t)N * 4, stream);

    wconv_kernel<<<48, 256, 0, stream>>>(Wq, Wk, Wh, Wsw);
    gemm_mfma_kernel<<<GB + 512, 256, 0, stream>>>(x, Wsw, bh, QL, KH, N,
                                                   ei, E, deg, epos, GB);
    bsum_kernel<<<NB, 1024, 0, stream>>>(deg, N, bsum);
    bscan_kernel<<<1, 1024, 0, stream>>>(bsum, NB, rowstart, N);
    scan_apply_kernel<<<NB, 1024, 0, stream>>>(deg, bsum, N, rowstart);
    fill_kernel<<<(E + 255) / 256, 256, 0, stream>>>(ei, E, rowstart, epos, csr_col);

    // attention: two head-pair passes (working set halved per pass)
    const int AB = (N + 3) / 4;
    attn_kernel<<<AB, 256, 0, stream>>>(QL, KH, rowstart, csr_col, out, N, 0);
    attn_kernel<<<AB, 256, 0, stream>>>(QL, KH, rowstart, csr_col, out, N, 1);
}